// Round 5
// baseline (840.840 us; speedup 1.0000x reference)
//
#include <hip/hip_runtime.h>
#include <math.h>
#include <stdint.h>

constexpr int Nn = 64, Cc = 64, Tt = 300, Vv = 25, Ff = 64;
constexpr int TP = Tt / 2;             // 150 t-pairs per n
constexpr float ALPHA = 0.2f;
constexpr float NEG_INF = -9.0e15f;

// ---- prep kernel (1 block, runs once per graph replay, ~3 us) ----
// ws layout: float[0..128)  = Wa interleaved: ws[2c]=W[:,c]... (Wa1[c],Wa2[c])
//            uint  [128..153) = adj row bitmasks
__global__ void prep_kernel(const float* __restrict__ W, const float* __restrict__ a,
                            const int* __restrict__ adj, float* __restrict__ ws) {
    const int tid = threadIdx.x;           // 256
    __shared__ float red[4][2][Cc];
    const int c = tid & 63, g = tid >> 6;  // g = f-quarter
    float s1 = 0.f, s2 = 0.f;
    #pragma unroll
    for (int q = 0; q < 16; ++q) {
        const int f = g * 16 + q;
        const float w = W[c * Ff + f];
        s1 += w * a[f];
        s2 += w * a[Ff + f];
    }
    red[g][0][c] = s1; red[g][1][c] = s2;
    __syncthreads();
    if (tid < Cc) {
        ws[2 * tid + 0] = red[0][0][tid] + red[1][0][tid] + red[2][0][tid] + red[3][0][tid];
        ws[2 * tid + 1] = red[0][1][tid] + red[1][1][tid] + red[2][1][tid] + red[3][1][tid];
    } else if (tid >= 64 && tid < 64 + Vv) {
        const int i = tid - 64;
        unsigned m = 0;
        #pragma unroll
        for (int j = 0; j < Vv; ++j) m |= (adj[i * Vv + j] > 0 ? 1u : 0u) << j;
        ((uint32_t*)ws)[128 + i] = m;
    }
}

__global__ __launch_bounds__(256, 6) void gat_kernel(
    const float* __restrict__ x,    // (N,C,T,V)
    const float* __restrict__ W,    // (C,F)
    const float* __restrict__ ws,   // prep output (Wa + adj masks)
    float* __restrict__ out)        // (N,F,T,V)
{
    // 25,700 B raw -> 6 blocks/CU by LDS
    __shared__ float xs[2][Cc][Vv];        // 12800 B  x staged (stride 25: reads conflict-free)
    __shared__ float hs[2][Vv][64];        // 12800 B  h[v][f], q-block XOR swizzled
    __shared__ unsigned adjm[Vv];          // 100 B

    const int tid = threadIdx.x;
    const int blk = blockIdx.x;            // n*TP + tp
    const int n = blk / TP, tp = blk - n * TP;
    const int t0 = tp * 2;

    // ---- staging: x slice (2 t's, all c) -> LDS (round-1-proven shape) ----
    {
        const float* xb = x + (size_t)(n * Cc * Tt + t0) * Vv;
        const int j = tid & 63, cg = tid >> 6;
        const int pp = (j >= Vv) ? 1 : 0;
        const int vj = j - Vv * pp;
        if (j < 2 * Vv) {
            #pragma unroll
            for (int i = 0; i < 16; ++i) {
                const int c = i * 4 + cg;
                xs[pp][c][vj] = xb[(size_t)c * (Tt * Vv) + j];
            }
        }
    }
    if (tid < Vv) adjm[tid] = ((const uint32_t*)ws)[128 + tid];
    __syncthreads();

    const int wid  = tid >> 6;
    const int lane = tid & 63;
    const int ph   = lane >> 5;            // which t of the pair
    const int v    = lane & 31;            // active v < 25
    const int vL   = (v < Vv) ? v : 0;     // clamp for loads
    const int f0   = __builtin_amdgcn_readfirstlane(wid << 4);  // wave-uniform f base
    const int sw   = v & 3;                // write-side q-XOR key
    const int phb  = lane & 32;            // ph*32, shfl base

    // ---- Phase B: acc[k]=sum_c x*W[c][f0+k]; p1/p2 = sum_c x*Wa (full dots!) ----
    // x via LDS + W via wave-uniform s_load, unroll 4: the proven clean-codegen shape.
    float acc[16];
    #pragma unroll
    for (int k = 0; k < 16; ++k) acc[k] = 0.f;
    float p1 = 0.f, p2 = 0.f;

    const float* __restrict__ Wg = W + f0;         // wave-uniform -> s_load
    const float* xcol = &xs[ph][0][vL];            // per-lane, stride 25 per c

    #pragma unroll 4
    for (int c = 0; c < Cc; ++c) {
        const float xv = xcol[c * Vv];
        const float4 w0 = *(const float4*)(Wg + c * Ff + 0);
        const float4 w1 = *(const float4*)(Wg + c * Ff + 4);
        const float4 w2 = *(const float4*)(Wg + c * Ff + 8);
        const float4 w3 = *(const float4*)(Wg + c * Ff + 12);
        const float2 wac = *(const float2*)(ws + 2 * c);   // uniform -> s_load_dwordx2
        acc[0]  += xv * w0.x; acc[1]  += xv * w0.y; acc[2]  += xv * w0.z; acc[3]  += xv * w0.w;
        acc[4]  += xv * w1.x; acc[5]  += xv * w1.y; acc[6]  += xv * w1.z; acc[7]  += xv * w1.w;
        acc[8]  += xv * w2.x; acc[9]  += xv * w2.y; acc[10] += xv * w2.z; acc[11] += xv * w2.w;
        acc[12] += xv * w3.x; acc[13] += xv * w3.y; acc[14] += xv * w3.z; acc[15] += xv * w3.w;
        p1 += xv * wac.x;
        p2 += xv * wac.y;
    }

    if (v < Vv) {
        #pragma unroll
        for (int q = 0; q < 4; ++q) {
            float4 t4;
            t4.x = acc[q * 4 + 0]; t4.y = acc[q * 4 + 1];
            t4.z = acc[q * 4 + 2]; t4.w = acc[q * 4 + 3];
            *(float4*)&hs[ph][v][f0 + 4 * (q ^ sw)] = t4;   // swizzled store
        }
    }

    // ---- Phase D: per-lane softmax scores for row v (all waves, redundant, no LDS) ----
    const unsigned m = adjm[vL];
    float z[Vv];
    float mx = -INFINITY;
    #pragma unroll
    for (int j = 0; j < Vv; ++j) {
        const float f2j = __shfl(p2, phb + j, 64);   // f2[j] lives in lane ph*32+j
        float zz = p1 + f2j;
        zz = (zz > 0.f) ? zz : ALPHA * zz;           // leaky_relu BEFORE mask
        zz = ((m >> j) & 1u) ? zz : NEG_INF;
        z[j] = zz; mx = fmaxf(mx, zz);
    }
    __syncthreads();   // hs ready

    // ---- Phase E: acc2 = sum_j exp(z[j]-mx)*h[j][fslice]; normalize once ----
    float acc2[16];
    #pragma unroll
    for (int k = 0; k < 16; ++k) acc2[k] = 0.f;
    float s = 0.f;
    #pragma unroll
    for (int j = 0; j < Vv; ++j) {
        const float e = __expf(z[j] - mx);
        s += e;
        const int K = j & 3;                         // compile-time per unrolled j
        const float4 h0 = *(const float4*)&hs[ph][j][f0 + 4 * (0 ^ K)];
        const float4 h1 = *(const float4*)&hs[ph][j][f0 + 4 * (1 ^ K)];
        const float4 h2 = *(const float4*)&hs[ph][j][f0 + 4 * (2 ^ K)];
        const float4 h3 = *(const float4*)&hs[ph][j][f0 + 4 * (3 ^ K)];
        acc2[0]  += e * h0.x; acc2[1]  += e * h0.y; acc2[2]  += e * h0.z; acc2[3]  += e * h0.w;
        acc2[4]  += e * h1.x; acc2[5]  += e * h1.y; acc2[6]  += e * h1.z; acc2[7]  += e * h1.w;
        acc2[8]  += e * h2.x; acc2[9]  += e * h2.y; acc2[10] += e * h2.z; acc2[11] += e * h2.w;
        acc2[12] += e * h3.x; acc2[13] += e * h3.y; acc2[14] += e * h3.z; acc2[15] += e * h3.w;
    }
    const float inv = 1.f / s;

    // ---- Phase F: normalize + elu + direct register->global writeout ----
    if (v < Vv) {
        float* ob = out + ((size_t)(n * Ff + f0) * Tt + (size_t)(t0 + ph)) * Vv + v;
        #pragma unroll
        for (int k = 0; k < 16; ++k) {
            float zo = acc2[k] * inv;
            zo = (zo > 0.f) ? zo : (__expf(zo) - 1.f);   // elu(alpha=1)
            ob[(size_t)k * Tt * Vv] = zo;
        }
    }
}

extern "C" void kernel_launch(void* const* d_in, const int* in_sizes, int n_in,
                              void* d_out, int out_size, void* d_ws, size_t ws_size,
                              hipStream_t stream) {
    const float* x   = (const float*)d_in[0];
    const int*   adj = (const int*)d_in[1];
    const float* W   = (const float*)d_in[2];
    const float* a   = (const float*)d_in[3];
    float* out = (float*)d_out;
    float* ws  = (float*)d_ws;

    prep_kernel<<<dim3(1), dim3(256), 0, stream>>>(W, a, adj, ws);
    gat_kernel<<<dim3(Nn * TP), dim3(256), 0, stream>>>(x, W, ws, out);
}

// Round 6
// 688.576 us; speedup vs baseline: 1.2211x; 1.2211x over previous
//
#include <hip/hip_runtime.h>
#include <math.h>
#include <stdint.h>

constexpr int Nn = 64, Cc = 64, Tt = 300, Vv = 25, Ff = 64;
constexpr int TP = Tt / 2;             // 150 t-pairs per n
constexpr float ALPHA = 0.2f;
constexpr float NEG_INF = -9.0e15f;

// ---- prep kernel (1 block, ~3 us) ----
// ws layout: float[0..128)   = interleaved (Wa1[c], Wa2[c]) = (W @ a1, W @ a2)
//            uint [128..153) = adj row bitmasks
__global__ void prep_kernel(const float* __restrict__ W, const float* __restrict__ a,
                            const int* __restrict__ adj, float* __restrict__ ws) {
    const int tid = threadIdx.x;           // 256
    __shared__ float red[4][2][Cc];
    const int c = tid & 63, g = tid >> 6;  // g = f-quarter
    float s1 = 0.f, s2 = 0.f;
    #pragma unroll
    for (int q = 0; q < 16; ++q) {
        const int f = g * 16 + q;
        const float w = W[c * Ff + f];
        s1 += w * a[f];
        s2 += w * a[Ff + f];
    }
    red[g][0][c] = s1; red[g][1][c] = s2;
    __syncthreads();
    if (tid < Cc) {
        ws[2 * tid + 0] = red[0][0][tid] + red[1][0][tid] + red[2][0][tid] + red[3][0][tid];
        ws[2 * tid + 1] = red[0][1][tid] + red[1][1][tid] + red[2][1][tid] + red[3][1][tid];
    } else if (tid >= 64 && tid < 64 + Vv) {
        const int i = tid - 64;
        unsigned m = 0;
        #pragma unroll
        for (int j = 0; j < Vv; ++j) m |= (adj[i * Vv + j] > 0 ? 1u : 0u) << j;
        ((uint32_t*)ws)[128 + i] = m;
    }
}

// waves_per_eu(4,4): pin the scheduler's occupancy TARGET to 4 waves/EU ->
// 128-VGPR budget. launch_bounds' 2nd arg is only a MIN; with small LDS the
// scheduler otherwise targets the LDS-derived max (6-8 waves/EU), which on
// gfx950 requires VGPR<=64 and spills this ~90-reg kernel (rounds 2-5).
__global__ void __launch_bounds__(256)
__attribute__((amdgpu_waves_per_eu(4, 4))) gat_kernel(
    const float* __restrict__ x,    // (N,C,T,V)
    const float* __restrict__ W,    // (C,F)
    const float* __restrict__ ws,   // prep output (Wa + adj masks)
    float* __restrict__ out)        // (N,F,T,V)
{
    __shared__ float xs[2][Cc][Vv];        // 12800 B  x staged (stride 25: odd -> conflict-free)
    __shared__ float hs[2][Vv][64];        // 12800 B  h[v][f], q-block XOR swizzled

    const int tid = threadIdx.x;
    const int blk = blockIdx.x;            // n*TP + tp
    const int n = blk / TP, tp = blk - n * TP;
    const int t0 = tp * 2;

    // ---- staging: x slice (2 t's, all c) -> LDS (round-1-proven shape) ----
    {
        const float* xb = x + (size_t)(n * Cc * Tt + t0) * Vv;
        const int j = tid & 63, cg = tid >> 6;
        const int pp = (j >= Vv) ? 1 : 0;
        const int vj = j - Vv * pp;
        if (j < 2 * Vv) {
            #pragma unroll
            for (int i = 0; i < 16; ++i) {
                const int c = i * 4 + cg;
                xs[pp][c][vj] = xb[(size_t)c * (Tt * Vv) + j];
            }
        }
    }
    __syncthreads();

    const int wid  = tid >> 6;
    const int lane = tid & 63;
    const int ph   = lane >> 5;            // which t of the pair
    const int v    = lane & 31;            // active v < 25
    const int vL   = (v < Vv) ? v : 0;     // clamp for loads
    const int f0   = __builtin_amdgcn_readfirstlane(wid << 4);  // wave-uniform f base
    const int sw   = v & 3;                // write-side q-XOR key
    const int phb  = lane & 32;            // ph*32, shfl base

    // ---- Phase B: acc[k]=sum_c x*W[c][f0+k]; p1/p2 = sum_c x*Wa (full dots) ----
    float acc[16];
    #pragma unroll
    for (int k = 0; k < 16; ++k) acc[k] = 0.f;
    float p1 = 0.f, p2 = 0.f;

    const float* __restrict__ Wg = W + f0;         // wave-uniform -> s_load
    const float* xcol = &xs[ph][0][vL];            // per-lane, stride 25 per c

    #pragma unroll 4
    for (int c = 0; c < Cc; ++c) {
        const float xv = xcol[c * Vv];
        const float4 w0 = *(const float4*)(Wg + c * Ff + 0);
        const float4 w1 = *(const float4*)(Wg + c * Ff + 4);
        const float4 w2 = *(const float4*)(Wg + c * Ff + 8);
        const float4 w3 = *(const float4*)(Wg + c * Ff + 12);
        const float2 wac = *(const float2*)(ws + 2 * c);   // uniform -> s_load
        acc[0]  += xv * w0.x; acc[1]  += xv * w0.y; acc[2]  += xv * w0.z; acc[3]  += xv * w0.w;
        acc[4]  += xv * w1.x; acc[5]  += xv * w1.y; acc[6]  += xv * w1.z; acc[7]  += xv * w1.w;
        acc[8]  += xv * w2.x; acc[9]  += xv * w2.y; acc[10] += xv * w2.z; acc[11] += xv * w2.w;
        acc[12] += xv * w3.x; acc[13] += xv * w3.y; acc[14] += xv * w3.z; acc[15] += xv * w3.w;
        p1 += xv * wac.x;
        p2 += xv * wac.y;
    }

    if (v < Vv) {
        #pragma unroll
        for (int q = 0; q < 4; ++q) {
            float4 t4;
            t4.x = acc[q * 4 + 0]; t4.y = acc[q * 4 + 1];
            t4.z = acc[q * 4 + 2]; t4.w = acc[q * 4 + 3];
            *(float4*)&hs[ph][v][f0 + 4 * (q ^ sw)] = t4;   // swizzled store
        }
    }

    // ---- Phase D: per-lane softmax scores for row v (all waves, no LDS) ----
    const unsigned m = ((const uint32_t*)ws)[128 + vL];   // L1-resident
    float z[Vv];
    float mx = -INFINITY;
    #pragma unroll
    for (int j = 0; j < Vv; ++j) {
        const float f2j = __shfl(p2, phb + j, 64);   // f2[j] lives in lane ph*32+j
        float zz = p1 + f2j;
        zz = (zz > 0.f) ? zz : ALPHA * zz;           // leaky_relu BEFORE mask
        zz = ((m >> j) & 1u) ? zz : NEG_INF;
        z[j] = zz; mx = fmaxf(mx, zz);
    }
    __syncthreads();   // hs ready

    // ---- Phase E: acc2 = sum_j exp(z[j]-mx)*h[j][fslice]; normalize once ----
    float acc2[16];
    #pragma unroll
    for (int k = 0; k < 16; ++k) acc2[k] = 0.f;
    float s = 0.f;
    #pragma unroll
    for (int j = 0; j < Vv; ++j) {
        const float e = __expf(z[j] - mx);
        s += e;
        const int K = j & 3;                         // compile-time per unrolled j
        const float4 h0 = *(const float4*)&hs[ph][j][f0 + 4 * (0 ^ K)];
        const float4 h1 = *(const float4*)&hs[ph][j][f0 + 4 * (1 ^ K)];
        const float4 h2 = *(const float4*)&hs[ph][j][f0 + 4 * (2 ^ K)];
        const float4 h3 = *(const float4*)&hs[ph][j][f0 + 4 * (3 ^ K)];
        acc2[0]  += e * h0.x; acc2[1]  += e * h0.y; acc2[2]  += e * h0.z; acc2[3]  += e * h0.w;
        acc2[4]  += e * h1.x; acc2[5]  += e * h1.y; acc2[6]  += e * h1.z; acc2[7]  += e * h1.w;
        acc2[8]  += e * h2.x; acc2[9]  += e * h2.y; acc2[10] += e * h2.z; acc2[11] += e * h2.w;
        acc2[12] += e * h3.x; acc2[13] += e * h3.y; acc2[14] += e * h3.z; acc2[15] += e * h3.w;
    }
    const float inv = 1.f / s;

    // ---- Phase F: normalize + elu + direct register->global writeout ----
    if (v < Vv) {
        float* ob = out + ((size_t)(n * Ff + f0) * Tt + (size_t)(t0 + ph)) * Vv + v;
        #pragma unroll
        for (int k = 0; k < 16; ++k) {
            float zo = acc2[k] * inv;
            zo = (zo > 0.f) ? zo : (__expf(zo) - 1.f);   // elu(alpha=1)
            ob[(size_t)k * Tt * Vv] = zo;
        }
    }
}

extern "C" void kernel_launch(void* const* d_in, const int* in_sizes, int n_in,
                              void* d_out, int out_size, void* d_ws, size_t ws_size,
                              hipStream_t stream) {
    const float* x   = (const float*)d_in[0];
    const int*   adj = (const int*)d_in[1];
    const float* W   = (const float*)d_in[2];
    const float* a   = (const float*)d_in[3];
    float* out = (float*)d_out;
    float* ws  = (float*)d_ws;

    prep_kernel<<<dim3(1), dim3(256), 0, stream>>>(W, a, adj, ws);
    gat_kernel<<<dim3(Nn * TP), dim3(256), 0, stream>>>(x, W, ws, out);
}